// Round 1
// baseline (771.491 us; speedup 1.0000x reference)
//
#include <hip/hip_runtime.h>

// Problem dims
#define B_    8
#define N_    1024
#define DIN   512
#define H_    8
#define DH    64
#define DQKV  6144   // 2*DQ + 2*DQ + DV = 512+512+512+512+4096
#define DEXP  2048
#define DTIME 256

typedef __attribute__((ext_vector_type(8))) short s16x8;   // 8 bf16 (MFMA A/B frag)
typedef __attribute__((ext_vector_type(4))) short s16x4;
typedef __attribute__((ext_vector_type(4))) float f32x4;   // MFMA C/D frag

__device__ __forceinline__ unsigned short f2bf(float f) {
  unsigned int u = __float_as_uint(f);
  u = (u + 0x7fffu + ((u >> 16) & 1u)) >> 16;   // RNE
  return (unsigned short)u;
}

// ---------------- LayerNorm (D=512), optional per-batch additive row, bf16 out ----
__global__ __launch_bounds__(256) void ln_k(
    const float* __restrict__ x, const float* __restrict__ add,
    const float* __restrict__ g, const float* __restrict__ bb,
    unsigned short* __restrict__ out)
{
  int row = blockIdx.x;
  int tid = threadIdx.x;
  const float* xr = x + (size_t)row * DIN;
  float v0 = xr[tid], v1 = xr[tid + 256];
  if (add) {
    const float* ar = add + (size_t)(row >> 10) * DIN;   // row/1024 = batch idx
    v0 += ar[tid]; v1 += ar[tid + 256];
  }
  float s = v0 + v1, sq = v0 * v0 + v1 * v1;
  #pragma unroll
  for (int m = 1; m < 64; m <<= 1) { s += __shfl_xor(s, m, 64); sq += __shfl_xor(sq, m, 64); }
  __shared__ float red[8];
  int w = tid >> 6;
  if ((tid & 63) == 0) { red[w] = s; red[4 + w] = sq; }
  __syncthreads();
  s  = red[0] + red[1] + red[2] + red[3];
  sq = red[4] + red[5] + red[6] + red[7];
  float mean = s * (1.0f / DIN);
  float var  = sq * (1.0f / DIN) - mean * mean;
  float rs = rsqrtf(var + 1e-5f);
  unsigned short* orow = out + (size_t)row * DIN;
  orow[tid]       = f2bf((v0 - mean) * rs * g[tid]       + bb[tid]);
  orow[tid + 256] = f2bf((v1 - mean) * rs * g[tid + 256] + bb[tid + 256]);
}

// ---------------- f32 [R][C] -> bf16 [C][R] transpose (weights) ------------------
__global__ __launch_bounds__(256) void wtrans_k(
    const float* __restrict__ in, unsigned short* __restrict__ out, int R, int C)
{
  __shared__ float tile[32][33];
  int tx = threadIdx.x & 31, ty = threadIdx.x >> 5;
  int c0 = blockIdx.x * 32, r0 = blockIdx.y * 32;
  #pragma unroll
  for (int k = 0; k < 4; ++k)
    tile[ty + k * 8][tx] = in[(size_t)(r0 + ty + k * 8) * C + c0 + tx];
  __syncthreads();
  #pragma unroll
  for (int k = 0; k < 4; ++k)
    out[(size_t)(c0 + ty + k * 8) * R + r0 + tx] = f2bf(tile[tx][ty + k * 8]);
}

// ---------------- V region of qkv -> Vt [bh][c(512)][kv(1024)] bf16 --------------
__global__ __launch_bounds__(256) void vtrans_k(
    const unsigned short* __restrict__ qkv, unsigned short* __restrict__ vt)
{
  __shared__ unsigned short tile[32][34];
  int tx = threadIdx.x & 31, ty = threadIdx.x >> 5;
  int c0 = blockIdx.x * 32, kv0 = blockIdx.y * 32, bh = blockIdx.z;
  int b = bh >> 3, h = bh & 7;
  #pragma unroll
  for (int k = 0; k < 4; ++k)
    tile[ty + k * 8][tx] =
      qkv[(size_t)(b * N_ + kv0 + ty + k * 8) * DQKV + 2048 + h * 512 + c0 + tx];
  __syncthreads();
  #pragma unroll
  for (int k = 0; k < 4; ++k)
    vt[(size_t)(bh * 512 + c0 + ty + k * 8) * N_ + kv0 + tx] = tile[tx][ty + k * 8];
}

// ---------------- time MLP: tp[b][512] = swish(t@Wt1+bt1)@Wt2+bt2 ---------------
__global__ __launch_bounds__(256) void time_k(
    const float* __restrict__ t, const float* __restrict__ Wt1, const float* __restrict__ bt1,
    const float* __restrict__ Wt2, const float* __restrict__ bt2, float* __restrict__ tp)
{
  int b = blockIdx.x, tid = threadIdx.x;
  __shared__ float tl[256], hl[256];
  tl[tid] = t[(size_t)b * 256 + tid];
  __syncthreads();
  float a = bt1[tid];
  for (int k = 0; k < 256; ++k) a += tl[k] * Wt1[(size_t)k * 256 + tid];
  hl[tid] = a / (1.0f + __expf(-a));
  __syncthreads();
  for (int j = tid; j < 512; j += 256) {
    float a2 = bt2[j];
    for (int k = 0; k < 256; ++k) a2 += hl[k] * Wt2[(size_t)k * 512 + j];
    tp[(size_t)b * 512 + j] = a2;
  }
}

// ---------------- bf16 MFMA GEMM: C = epi(A @ Bt^T + bias [+res]) ---------------
// A [M][lda] bf16 ; Bt [N][K] bf16 ; 128x128 tile, BK=32, 4 waves (2x2 of 64x64)
// EPI: 0 = bias -> bf16 ; 1 = bias+swish -> bf16 ; 2 = bias+res(f32) -> f32
template<int EPI>
__global__ __launch_bounds__(256) void gemm_bt(
    const unsigned short* __restrict__ A, int lda,
    const unsigned short* __restrict__ Bt,
    const float* __restrict__ bias, const float* __restrict__ res,
    void* __restrict__ C, int ldc, int N, int K)
{
  __shared__ __attribute__((aligned(16))) unsigned short As[128][40]; // +8 pad: 2-way banks
  __shared__ __attribute__((aligned(16))) unsigned short Bs[128][40];
  int tid = threadIdx.x;
  int m0 = blockIdx.y * 128, n0 = blockIdx.x * 128;
  int lane = tid & 63, wid = tid >> 6;
  int wr = wid >> 1, wc = wid & 1;
  int lr = lane & 15, lg = lane >> 4, lk = lg * 8;
  f32x4 zero = {0.f, 0.f, 0.f, 0.f};
  f32x4 acc[4][4];
  #pragma unroll
  for (int i = 0; i < 4; ++i)
    #pragma unroll
    for (int j = 0; j < 4; ++j) acc[i][j] = zero;
  int srow = tid >> 2, skk = (tid & 3) * 8;   // 64 rows x 4 chunks per half
  for (int kt = 0; kt < K; kt += 32) {
    *(s16x8*)&As[srow][skk]      = *(const s16x8*)(A  + (size_t)(m0 + srow)      * lda + kt + skk);
    *(s16x8*)&As[srow + 64][skk] = *(const s16x8*)(A  + (size_t)(m0 + srow + 64) * lda + kt + skk);
    *(s16x8*)&Bs[srow][skk]      = *(const s16x8*)(Bt + (size_t)(n0 + srow)      * K   + kt + skk);
    *(s16x8*)&Bs[srow + 64][skk] = *(const s16x8*)(Bt + (size_t)(n0 + srow + 64) * K   + kt + skk);
    __syncthreads();
    s16x8 af[4], bf[4];
    #pragma unroll
    for (int mf = 0; mf < 4; ++mf) af[mf] = *(const s16x8*)&As[wr * 64 + mf * 16 + lr][lk];
    #pragma unroll
    for (int nf = 0; nf < 4; ++nf) bf[nf] = *(const s16x8*)&Bs[wc * 64 + nf * 16 + lr][lk];
    #pragma unroll
    for (int mf = 0; mf < 4; ++mf)
      #pragma unroll
      for (int nf = 0; nf < 4; ++nf)
        acc[mf][nf] = __builtin_amdgcn_mfma_f32_16x16x32_bf16(af[mf], bf[nf], acc[mf][nf], 0, 0, 0);
    __syncthreads();
  }
  #pragma unroll
  for (int mf = 0; mf < 4; ++mf)
    #pragma unroll
    for (int nf = 0; nf < 4; ++nf) {
      int col = n0 + wc * 64 + nf * 16 + lr;
      float bcol = bias[col];
      #pragma unroll
      for (int r = 0; r < 4; ++r) {
        int row = m0 + wr * 64 + mf * 16 + lg * 4 + r;
        float v = acc[mf][nf][r] + bcol;
        if (EPI == 1) v = v / (1.0f + __expf(-v));            // swish
        if (EPI == 2) {
          v += res[(size_t)row * N + col];
          ((float*)C)[(size_t)row * ldc + col] = v;
        } else {
          ((unsigned short*)C)[(size_t)row * ldc + col] = f2bf(v);
        }
      }
    }
}

// ---------------- attention pass A: exact row stats (m,l) for both softmaxes ----
// block = (b,h,qtile of 64 rows), 4 waves; wave w owns rows w*16..w*16+15
__global__ __launch_bounds__(256) void attn_stats_k(
    const unsigned short* __restrict__ qkv,
    float* __restrict__ stm1, float* __restrict__ stl1,
    float* __restrict__ stm2, float* __restrict__ stl2)
{
  const float scale = 0.125f;
  int bx = blockIdx.x;
  int bh = bx >> 4, qt = bx & 15;
  int b = bh >> 3, h = bh & 7;
  int tid = threadIdx.x;
  int lane = tid & 63, w = tid >> 6;
  int lr = lane & 15, lg = lane >> 4, lk = lg * 8;
  size_t qrowoff = (size_t)(b * N_ + qt * 64 + w * 16 + lr) * DQKV;
  int qc1 = h * 64, qc2 = 512 + h * 64, kc1 = 1024 + h * 64, kc2 = 1536 + h * 64;
  s16x8 q1f[2], q2f[2];
  #pragma unroll
  for (int kf = 0; kf < 2; ++kf) {
    q1f[kf] = *(const s16x8*)(qkv + qrowoff + qc1 + kf * 32 + lk);
    q2f[kf] = *(const s16x8*)(qkv + qrowoff + qc2 + kf * 32 + lk);
  }
  float m1[4], l1[4], m2[4], l2[4];
  #pragma unroll
  for (int r = 0; r < 4; ++r) { m1[r] = -1e30f; l1[r] = 0.f; m2[r] = -1e30f; l2[r] = 0.f; }
  f32x4 zero = {0.f, 0.f, 0.f, 0.f};
  for (int kt = 0; kt < 16; ++kt) {
    f32x4 s1[4], s2[4];
    #pragma unroll
    for (int nf = 0; nf < 4; ++nf) {
      s1[nf] = zero; s2[nf] = zero;
      size_t krowoff = (size_t)(b * N_ + kt * 64 + nf * 16 + lr) * DQKV;
      #pragma unroll
      for (int kf = 0; kf < 2; ++kf) {
        s16x8 k1f = *(const s16x8*)(qkv + krowoff + kc1 + kf * 32 + lk);
        s16x8 k2f = *(const s16x8*)(qkv + krowoff + kc2 + kf * 32 + lk);
        s1[nf] = __builtin_amdgcn_mfma_f32_16x16x32_bf16(q1f[kf], k1f, s1[nf], 0, 0, 0);
        s2[nf] = __builtin_amdgcn_mfma_f32_16x16x32_bf16(q2f[kf], k2f, s2[nf], 0, 0, 0);
      }
    }
    #pragma unroll
    for (int r = 0; r < 4; ++r) {
      {
        float v0 = s1[0][r] * scale, v1 = s1[1][r] * scale, v2 = s1[2][r] * scale, v3 = s1[3][r] * scale;
        float tm = fmaxf(fmaxf(v0, v1), fmaxf(v2, v3));
        #pragma unroll
        for (int m = 1; m < 16; m <<= 1) tm = fmaxf(tm, __shfl_xor(tm, m, 64));
        float mn = fmaxf(m1[r], tm);
        float ps = __expf(v0 - mn) + __expf(v1 - mn) + __expf(v2 - mn) + __expf(v3 - mn);
        #pragma unroll
        for (int m = 1; m < 16; m <<= 1) ps += __shfl_xor(ps, m, 64);
        l1[r] = l1[r] * __expf(m1[r] - mn) + ps; m1[r] = mn;
      }
      {
        float v0 = s2[0][r] * scale, v1 = s2[1][r] * scale, v2 = s2[2][r] * scale, v3 = s2[3][r] * scale;
        float tm = fmaxf(fmaxf(v0, v1), fmaxf(v2, v3));
        #pragma unroll
        for (int m = 1; m < 16; m <<= 1) tm = fmaxf(tm, __shfl_xor(tm, m, 64));
        float mn = fmaxf(m2[r], tm);
        float ps = __expf(v0 - mn) + __expf(v1 - mn) + __expf(v2 - mn) + __expf(v3 - mn);
        #pragma unroll
        for (int m = 1; m < 16; m <<= 1) ps += __shfl_xor(ps, m, 64);
        l2[r] = l2[r] * __expf(m2[r] - mn) + ps; m2[r] = mn;
      }
    }
  }
  if (lr == 0) {
    #pragma unroll
    for (int r = 0; r < 4; ++r) {
      int idx = bh * N_ + qt * 64 + w * 16 + lg * 4 + r;
      stm1[idx] = m1[r]; stl1[idx] = l1[r]; stm2[idx] = m2[r]; stl2[idx] = l2[r];
    }
  }
}

// ---------------- attention pass B: P = e1/l1 - lam*e2/l2 ; O = P @ V -----------
// block = (b,h,qtile of 32 rows), 8 waves. Waves 0-3 compute S1 col-quadrants,
// waves 4-7 S2; all waves form P; wave w does PV for vcols [w*64, w*64+64).
__global__ __launch_bounds__(512) void attn_pv_k(
    const unsigned short* __restrict__ qkv, const unsigned short* __restrict__ vt,
    const float* __restrict__ stm1, const float* __restrict__ stl1,
    const float* __restrict__ stm2, const float* __restrict__ stl2,
    const float* __restrict__ lamp, unsigned short* __restrict__ aout /* = qkv+2048, ld DQKV */)
{
  const float scale = 0.125f;
  __shared__ __attribute__((aligned(16))) float S1[32][68];
  __shared__ __attribute__((aligned(16))) float S2[32][68];
  __shared__ __attribute__((aligned(16))) unsigned short P[32][72];
  int bx = blockIdx.x;
  int bh = bx >> 5, qt = bx & 31;
  int b = bh >> 3, h = bh & 7;
  int tid = threadIdx.x;
  int lane = tid & 63, w = tid >> 6;
  int lr = lane & 15, lg = lane >> 4, lk = lg * 8;
  int sw = w & 3;
  float lam = *lamp;
  int prow = tid >> 4, pcol0 = (tid & 15) * 4;
  int qglob = bh * N_ + qt * 32 + prow;
  float pm1 = stm1[qglob], pr1 = 1.f / stl1[qglob];
  float pm2 = stm2[qglob], pr2 = lam / stl2[qglob];
  int qcol = (w < 4) ? h * 64 : 512 + h * 64;
  int kcol = (w < 4) ? 1024 + h * 64 : 1536 + h * 64;
  s16x8 qf[2][2];
  #pragma unroll
  for (int mf = 0; mf < 2; ++mf)
    #pragma unroll
    for (int kf = 0; kf < 2; ++kf)
      qf[mf][kf] = *(const s16x8*)(qkv + (size_t)(b * N_ + qt * 32 + mf * 16 + lr) * DQKV
                                   + qcol + kf * 32 + lk);
  f32x4 zero = {0.f, 0.f, 0.f, 0.f};
  f32x4 O[2][4];
  #pragma unroll
  for (int mf = 0; mf < 2; ++mf)
    #pragma unroll
    for (int nf = 0; nf < 4; ++nf) O[mf][nf] = zero;
  for (int kt = 0; kt < 16; ++kt) {
    f32x4 sa[2]; sa[0] = zero; sa[1] = zero;
    #pragma unroll
    for (int kf = 0; kf < 2; ++kf) {
      s16x8 kfrag = *(const s16x8*)(qkv + (size_t)(b * N_ + kt * 64 + sw * 16 + lr) * DQKV
                                    + kcol + kf * 32 + lk);
      sa[0] = __builtin_amdgcn_mfma_f32_16x16x32_bf16(qf[0][kf], kfrag, sa[0], 0, 0, 0);
      sa[1] = __builtin_amdgcn_mfma_f32_16x16x32_bf16(qf[1][kf], kfrag, sa[1], 0, 0, 0);
    }
    float* Sd = (w < 4) ? &S1[0][0] : &S2[0][0];
    #pragma unroll
    for (int mf = 0; mf < 2; ++mf)
      #pragma unroll
      for (int r = 0; r < 4; ++r)
        Sd[(mf * 16 + lg * 4 + r) * 68 + sw * 16 + lr] = sa[mf][r] * scale;
    __syncthreads();
    s16x4 pv;
    #pragma unroll
    for (int j = 0; j < 4; ++j) {
      float e1 = __expf(S1[prow][pcol0 + j] - pm1) * pr1;
      float e2 = __expf(S2[prow][pcol0 + j] - pm2) * pr2;
      pv[j] = (short)f2bf(e1 - e2);
    }
    *(s16x4*)&P[prow][pcol0] = pv;
    __syncthreads();
    s16x8 pf[2][2];
    #pragma unroll
    for (int mf = 0; mf < 2; ++mf)
      #pragma unroll
      for (int kf = 0; kf < 2; ++kf)
        pf[mf][kf] = *(const s16x8*)&P[mf * 16 + lr][kf * 32 + lk];
    #pragma unroll
    for (int nf = 0; nf < 4; ++nf)
      #pragma unroll
      for (int kf = 0; kf < 2; ++kf) {
        s16x8 vf = *(const s16x8*)(vt + (size_t)(bh * 512 + w * 64 + nf * 16 + lr) * N_
                                   + kt * 64 + kf * 32 + lk);
        O[0][nf] = __builtin_amdgcn_mfma_f32_16x16x32_bf16(pf[0][kf], vf, O[0][nf], 0, 0, 0);
        O[1][nf] = __builtin_amdgcn_mfma_f32_16x16x32_bf16(pf[1][kf], vf, O[1][nf], 0, 0, 0);
      }
  }
  #pragma unroll
  for (int mf = 0; mf < 2; ++mf)
    #pragma unroll
    for (int nf = 0; nf < 4; ++nf) {
      int col = h * 512 + w * 64 + nf * 16 + lr;
      #pragma unroll
      for (int r = 0; r < 4; ++r) {
        int row = b * N_ + qt * 32 + mf * 16 + lg * 4 + r;
        aout[(size_t)row * DQKV + col] = f2bf(O[mf][nf][r]);
      }
    }
}

// ---------------------------------- launcher ------------------------------------
extern "C" void kernel_launch(void* const* d_in, const int* in_sizes, int n_in,
                              void* d_out, int out_size, void* d_ws, size_t ws_size,
                              hipStream_t stream) {
  const float* x    = (const float*)d_in[0];
  const float* t    = (const float*)d_in[1];
  const float* ln1g = (const float*)d_in[2];
  const float* ln1b = (const float*)d_in[3];
  const float* Wqkv = (const float*)d_in[4];
  const float* bqkv = (const float*)d_in[5];
  const float* lam  = (const float*)d_in[6];
  const float* Wm   = (const float*)d_in[7];
  const float* bm   = (const float*)d_in[8];
  const float* Wt1  = (const float*)d_in[9];
  const float* bt1  = (const float*)d_in[10];
  const float* Wt2  = (const float*)d_in[11];
  const float* bt2  = (const float*)d_in[12];
  const float* lnfg = (const float*)d_in[13];
  const float* lnfb = (const float*)d_in[14];
  const float* Wf1  = (const float*)d_in[15];
  const float* bf1  = (const float*)d_in[16];
  const float* Wf2  = (const float*)d_in[17];
  const float* bf2  = (const float*)d_in[18];
  float* out = (float*)d_out;
  char* ws = (char*)d_ws;

  // workspace layout (bytes), ~209 MB total
  unsigned short* qkv   = (unsigned short*)(ws);                  // [8192][6144] bf16 (100.7MB)
  unsigned short* vt    = (unsigned short*)(ws + 100663296ull);   // [64][512][1024] bf16 (67MB)
  float*          x2    = (float*)(ws + 167772160ull);            // [8192][512] f32 (16.8MB)
  unsigned short* xn    = (unsigned short*)(ws + 184549376ull);   // [8192][512] bf16 (xn, then h)
  float*          stm1  = (float*)(ws + 192937984ull);            // 4 x 65536 f32 stats
  float*          stl1  = stm1 + 65536;
  float*          stm2  = stm1 + 131072;
  float*          stl2  = stm1 + 196608;
  unsigned short* WqkvT = (unsigned short*)(ws + 193986560ull);   // [6144][512]
  unsigned short* WmT   = (unsigned short*)(ws + 200278016ull);   // [512][4096]
  unsigned short* Wf1T  = (unsigned short*)(ws + 204472320ull);   // [2048][512]
  unsigned short* Wf2T  = (unsigned short*)(ws + 206569472ull);   // [512][2048]
  float*          tp    = (float*)(ws + 208666624ull);            // [8][512]
  unsigned short* ff1s  = qkv;          // alias: qkv dead after attention
  unsigned short* aout  = qkv + 2048;   // alias: attention out over dead V region

  // weights -> bf16 transposed [N][K]
  wtrans_k<<<dim3(DQKV / 32, DIN / 32),  256, 0, stream>>>(Wqkv, WqkvT, DIN, DQKV);
  wtrans_k<<<dim3(DIN / 32, 4096 / 32),  256, 0, stream>>>(Wm,   WmT,   4096, DIN);
  wtrans_k<<<dim3(DEXP / 32, DIN / 32),  256, 0, stream>>>(Wf1,  Wf1T,  DIN, DEXP);
  wtrans_k<<<dim3(DIN / 32, DEXP / 32),  256, 0, stream>>>(Wf2,  Wf2T,  DEXP, DIN);
  // ln1 + time MLP
  ln_k<<<8192, 256, 0, stream>>>(x, nullptr, ln1g, ln1b, xn);
  time_k<<<8, 256, 0, stream>>>(t, Wt1, bt1, Wt2, bt2, tp);
  // qkv GEMM
  gemm_bt<0><<<dim3(DQKV / 128, 8192 / 128), 256, 0, stream>>>(
      xn, DIN, WqkvT, bqkv, nullptr, qkv, DQKV, DQKV, DIN);
  // V transpose, then two-pass differential attention
  vtrans_k<<<dim3(16, 32, 64), 256, 0, stream>>>(qkv, vt);
  attn_stats_k<<<1024, 256, 0, stream>>>(qkv, stm1, stl1, stm2, stl2);
  attn_pv_k<<<2048, 512, 0, stream>>>(qkv, vt, stm1, stl1, stm2, stl2, lam, aout);
  // x2 = x + attn_out @ Wm + bm
  gemm_bt<2><<<dim3(DIN / 128, 8192 / 128), 256, 0, stream>>>(
      aout, DQKV, WmT, bm, x, x2, DIN, DIN, 4096);
  // h = LN(x2 + tp)
  ln_k<<<8192, 256, 0, stream>>>(x2, tp, lnfg, lnfb, xn);
  // ff1 = swish(h @ Wf1 + bf1)
  gemm_bt<1><<<dim3(DEXP / 128, 8192 / 128), 256, 0, stream>>>(
      xn, DIN, Wf1T, bf1, nullptr, ff1s, DEXP, DEXP, DIN);
  // out = x2 + ff1 @ Wf2 + bf2
  gemm_bt<2><<<dim3(DIN / 128, 8192 / 128), 256, 0, stream>>>(
      ff1s, DEXP, Wf2T, bf2, x2, out, DIN, DIN, DEXP);
}